// Round 2
// baseline (370.840 us; speedup 1.0000x reference)
//
#include <hip/hip_runtime.h>

static constexpr int S_SYS  = 8;
static constexpr int E_PAIRS = 1000000;
static constexpr int N_A    = 20000;
static constexpr int NBINS  = 16;

// Kernel 1: per-pair switching function -> scatter-add onto per-system coords.
// 4 pairs per thread: 3 coalesced float4 + 1 int4 per thread (16B/lane).
// unsafeAtomicAdd -> native global_atomic_add_f32 (fire-and-forget), NOT a CAS loop.
__global__ __launch_bounds__(256) void coord_scatter(
    const float* __restrict__ vec, const int* __restrict__ atom,
    float* __restrict__ coords)
{
    const int P4 = S_SYS * E_PAIRS / 4;   // 2,000,000 thread-work items
    int stride = gridDim.x * blockDim.x;
    for (int t = blockIdx.x * blockDim.x + threadIdx.x; t < P4; t += stride) {
        const float4* v4 = reinterpret_cast<const float4*>(vec) + 3ull * (unsigned)t;
        float4 A = v4[0], B = v4[1], C = v4[2];
        int4 id = reinterpret_cast<const int4*>(atom)[t];

        // E_PAIRS % 4 == 0 so a 4-pair group never crosses a system boundary
        int s = (t * 4) / E_PAIRS;
        float* cs = coords + s * N_A;

        float px[4] = {A.x, A.w, B.z, C.y};
        float py[4] = {A.y, B.x, B.w, C.z};
        float pz[4] = {A.z, B.y, C.x, C.w};
        int ids[4]  = {id.x, id.y, id.z, id.w};

        #pragma unroll
        for (int j = 0; j < 4; ++j) {
            float d = sqrtf(px[j]*px[j] + py[j]*py[j] + pz[j]*pz[j]);
            float y = (d - 4.4f) / 1.1f;   // (d - R1) / (R0 - R1)
            float z;
            if (y <= 0.0f)      z = 1.0f;
            else if (y >= 1.0f) z = 0.0f;
            else { float u = y - 1.0f; z = u * u * (1.0f + 2.0f * y); }
            if (z != 0.0f) unsafeAtomicAdd(&cs[ids[j]], z);   // skip ~12% zero adds
        }
    }
}

// Kernel 2: KDE histogram. One block = 256 atoms of one system.
__global__ __launch_bounds__(256) void kde_reduce(
    const float* __restrict__ coords, float* __restrict__ out)
{
    int s = blockIdx.y;
    int a = blockIdx.x * 256 + threadIdx.x;
    bool valid = (a < N_A);
    float c = valid ? coords[s * N_A + a] : 0.0f;

    float vals[NBINS];
    #pragma unroll
    for (int k = 0; k < NBINS; ++k) {
        float d = c - (float)k;
        vals[k] = valid ? expf(-2.0f * d * d) : 0.0f;   // 0.5/SIGMA2 == 2 exactly
    }

    #pragma unroll
    for (int k = 0; k < NBINS; ++k) {
        #pragma unroll
        for (int off = 32; off > 0; off >>= 1)
            vals[k] += __shfl_down(vals[k], off, 64);
    }

    __shared__ float sbin[4][NBINS];
    int wave = threadIdx.x >> 6;
    int lane = threadIdx.x & 63;
    if (lane == 0) {
        #pragma unroll
        for (int k = 0; k < NBINS; ++k) sbin[wave][k] = vals[k];
    }
    __syncthreads();
    if (threadIdx.x < NBINS) {
        float v = sbin[0][threadIdx.x] + sbin[1][threadIdx.x]
                + sbin[2][threadIdx.x] + sbin[3][threadIdx.x];
        unsafeAtomicAdd(&out[s * NBINS + threadIdx.x], v);
    }
}

extern "C" void kernel_launch(void* const* d_in, const int* in_sizes, int n_in,
                              void* d_out, int out_size, void* d_ws, size_t ws_size,
                              hipStream_t stream) {
    const float* vec  = (const float*)d_in[0];   // neighbor_vectors [S,E,3] f32
    const int*   atom = (const int*)d_in[1];     // first_atom [S,E] i32
    float* out    = (float*)d_out;               // [S,16] f32
    float* coords = (float*)d_ws;                // [S, N_A] f32 scratch

    hipMemsetAsync(coords, 0, (size_t)S_SYS * N_A * sizeof(float), stream);
    hipMemsetAsync(out,    0, (size_t)S_SYS * NBINS * sizeof(float), stream);

    coord_scatter<<<2048, 256, 0, stream>>>(vec, atom, coords);

    dim3 g2((N_A + 255) / 256, S_SYS);
    kde_reduce<<<g2, 256, 0, stream>>>(coords, out);
}

// Round 3
// 74.146 us; speedup vs baseline: 5.0015x; 5.0015x over previous
//
#include <hip/hip_runtime.h>

static constexpr int S_SYS   = 8;
static constexpr int E_PAIRS = 1000000;
static constexpr int N_A     = 20000;
static constexpr int NBINS   = 16;
static constexpr int BPS_MAX = 64;        // partials per system (cap)

// ---------------- Fast path ----------------
// Kernel 1: each block privatizes a full per-system coords array in LDS (80 KB,
// 2 blocks/CU on gfx950's 160KB LDS), accumulates its slice of pairs with LDS
// atomics (ds_add_f32, on-CU), then streams its partial out with plain stores.
// Zero global atomics.
__global__ __launch_bounds__(256) void coord_lds(
    const float* __restrict__ vec, const int* __restrict__ atom,
    float* __restrict__ partial, int bps)
{
    __shared__ __align__(16) float lc[N_A];          // 80 KB
    for (int i = threadIdx.x; i < N_A; i += 256) lc[i] = 0.0f;
    __syncthreads();

    const int s = blockIdx.y;
    const int Q = E_PAIRS / 4;                        // 250,000 quad-groups/system
    const float4* vb = reinterpret_cast<const float4*>(vec) + (size_t)s * Q * 3;
    const int4*   ib = reinterpret_cast<const int4*>(atom) + (size_t)s * Q;

    const int stride = bps * 256;
    for (int t = blockIdx.x * 256 + threadIdx.x; t < Q; t += stride) {
        float4 A = vb[3 * t], B = vb[3 * t + 1], C = vb[3 * t + 2];
        int4 id = ib[t];

        float px[4] = {A.x, A.w, B.z, C.y};
        float py[4] = {A.y, B.x, B.w, C.z};
        float pz[4] = {A.z, B.y, C.x, C.w};
        int ids[4]  = {id.x, id.y, id.z, id.w};

        #pragma unroll
        for (int j = 0; j < 4; ++j) {
            float d = sqrtf(px[j]*px[j] + py[j]*py[j] + pz[j]*pz[j]);
            float y = (d - 4.4f) / 1.1f;              // (d - R1) / (R0 - R1)
            float z;
            if (y <= 0.0f)      z = 1.0f;
            else if (y >= 1.0f) z = 0.0f;
            else { float u = y - 1.0f; z = u * u * (1.0f + 2.0f * y); }
            if (z != 0.0f) atomicAdd(&lc[ids[j]], z); // ds_add_f32, on-CU
        }
    }
    __syncthreads();

    float4* po = reinterpret_cast<float4*>(partial + ((size_t)s * bps + blockIdx.x) * N_A);
    const float4* ls = reinterpret_cast<const float4*>(lc);
    for (int i = threadIdx.x; i < N_A / 4; i += 256) po[i] = ls[i];
}

// ---------------- Fallback path (ws too small): R1's global-atomic scatter ----
__global__ __launch_bounds__(256) void coord_scatter(
    const float* __restrict__ vec, const int* __restrict__ atom,
    float* __restrict__ coords)
{
    const int P4 = S_SYS * E_PAIRS / 4;
    int stride = gridDim.x * blockDim.x;
    for (int t = blockIdx.x * blockDim.x + threadIdx.x; t < P4; t += stride) {
        const float4* v4 = reinterpret_cast<const float4*>(vec) + 3ull * (unsigned)t;
        float4 A = v4[0], B = v4[1], C = v4[2];
        int4 id = reinterpret_cast<const int4*>(atom)[t];
        int s = (t * 4) / E_PAIRS;
        float* cs = coords + s * N_A;
        float px[4] = {A.x, A.w, B.z, C.y};
        float py[4] = {A.y, B.x, B.w, C.z};
        float pz[4] = {A.z, B.y, C.x, C.w};
        int ids[4]  = {id.x, id.y, id.z, id.w};
        #pragma unroll
        for (int j = 0; j < 4; ++j) {
            float d = sqrtf(px[j]*px[j] + py[j]*py[j] + pz[j]*pz[j]);
            float y = (d - 4.4f) / 1.1f;
            float z;
            if (y <= 0.0f)      z = 1.0f;
            else if (y >= 1.0f) z = 0.0f;
            else { float u = y - 1.0f; z = u * u * (1.0f + 2.0f * y); }
            if (z != 0.0f) unsafeAtomicAdd(&cs[ids[j]], z);
        }
    }
}

// Kernel 2: sum bps partials per atom, then KDE onto 16 bins.
// bps==1 degenerates to reading a plain coords array (fallback path).
__global__ __launch_bounds__(256) void kde_reduce(
    const float* __restrict__ partial, float* __restrict__ out, int bps)
{
    int s = blockIdx.y;
    int a = blockIdx.x * 256 + threadIdx.x;
    bool valid = (a < N_A);

    float c = 0.0f;
    if (valid) {
        const float* p = partial + (size_t)s * bps * N_A + a;
        for (int b = 0; b < bps; ++b) c += p[(size_t)b * N_A];
    }

    float vals[NBINS];
    #pragma unroll
    for (int k = 0; k < NBINS; ++k) {
        float d = c - (float)k;
        vals[k] = valid ? expf(-2.0f * d * d) : 0.0f;  // 0.5/SIGMA2 == 2
    }

    #pragma unroll
    for (int k = 0; k < NBINS; ++k) {
        #pragma unroll
        for (int off = 32; off > 0; off >>= 1)
            vals[k] += __shfl_down(vals[k], off, 64);
    }

    __shared__ float sbin[4][NBINS];
    int wave = threadIdx.x >> 6;
    int lane = threadIdx.x & 63;
    if (lane == 0) {
        #pragma unroll
        for (int k = 0; k < NBINS; ++k) sbin[wave][k] = vals[k];
    }
    __syncthreads();
    if (threadIdx.x < NBINS) {
        float v = sbin[0][threadIdx.x] + sbin[1][threadIdx.x]
                + sbin[2][threadIdx.x] + sbin[3][threadIdx.x];
        unsafeAtomicAdd(&out[s * NBINS + threadIdx.x], v);
    }
}

extern "C" void kernel_launch(void* const* d_in, const int* in_sizes, int n_in,
                              void* d_out, int out_size, void* d_ws, size_t ws_size,
                              hipStream_t stream) {
    const float* vec  = (const float*)d_in[0];   // [S,E,3] f32
    const int*   atom = (const int*)d_in[1];     // [S,E] i32
    float* out = (float*)d_out;                  // [S,16] f32
    float* ws  = (float*)d_ws;

    hipMemsetAsync(out, 0, (size_t)S_SYS * NBINS * sizeof(float), stream);

    // how many per-system partials fit in the workspace?
    int bps = (int)(ws_size / ((size_t)S_SYS * N_A * sizeof(float)));
    if (bps > BPS_MAX) bps = BPS_MAX;

    dim3 g2((N_A + 255) / 256, S_SYS);

    if (bps >= 4) {
        // fast path: LDS-privatized partials, no global atomics
        dim3 g1(bps, S_SYS);
        coord_lds<<<g1, 256, 0, stream>>>(vec, atom, ws, bps);
        kde_reduce<<<g2, 256, 0, stream>>>(ws, out, bps);
    } else {
        // fallback: global-atomic scatter into a single coords array
        hipMemsetAsync(ws, 0, (size_t)S_SYS * N_A * sizeof(float), stream);
        coord_scatter<<<2048, 256, 0, stream>>>(vec, atom, ws);
        kde_reduce<<<g2, 256, 0, stream>>>(ws, out, 1);
    }
}

// Round 4
// 72.663 us; speedup vs baseline: 5.1036x; 1.0204x over previous
//
#include <hip/hip_runtime.h>

static constexpr int S_SYS   = 8;
static constexpr int E_PAIRS = 1000000;
static constexpr int N_A     = 20000;
static constexpr int NBINS   = 16;
static constexpr int BPS_MAX = 64;        // partials per system (cap)
static constexpr int BLK     = 1024;      // 16 waves/block; 2 blocks/CU -> 32 waves/CU

// Kernel 1: per-block LDS-privatized coords (80 KB), ds_add_f32 accumulation,
// plain coalesced partial store. 1024-thread blocks + VGPR<=64 (launch_bounds
// min 8 waves/EU) so LDS and VGPR both allow 2 blocks/CU = full 32 waves/CU.
__global__ __launch_bounds__(BLK, 8) void coord_lds(
    const float* __restrict__ vec, const int* __restrict__ atom,
    float* __restrict__ partial, int bps)
{
    __shared__ __align__(16) float lc[N_A];          // 80 KB
    for (int i = threadIdx.x; i < N_A; i += BLK) lc[i] = 0.0f;
    __syncthreads();

    const int s = blockIdx.y;
    const int Q = E_PAIRS / 4;                        // 250,000 quad-groups/system
    const float4* vb = reinterpret_cast<const float4*>(vec) + (size_t)s * Q * 3;
    const int4*   ib = reinterpret_cast<const int4*>(atom) + (size_t)s * Q;

    const int stride = bps * BLK;
    for (int t = blockIdx.x * BLK + threadIdx.x; t < Q; t += stride) {
        float4 A = vb[3 * t], B = vb[3 * t + 1], C = vb[3 * t + 2];
        int4 id = ib[t];

        float px[4] = {A.x, A.w, B.z, C.y};
        float py[4] = {A.y, B.x, B.w, C.z};
        float pz[4] = {A.z, B.y, C.x, C.w};
        int ids[4]  = {id.x, id.y, id.z, id.w};

        #pragma unroll
        for (int j = 0; j < 4; ++j) {
            float d = sqrtf(px[j]*px[j] + py[j]*py[j] + pz[j]*pz[j]);
            float y = (d - 4.4f) / 1.1f;              // (d - R1) / (R0 - R1)
            float z;
            if (y <= 0.0f)      z = 1.0f;
            else if (y >= 1.0f) z = 0.0f;
            else { float u = y - 1.0f; z = u * u * (1.0f + 2.0f * y); }
            if (z != 0.0f) atomicAdd(&lc[ids[j]], z); // ds_add_f32, on-CU
        }
    }
    __syncthreads();

    float4* po = reinterpret_cast<float4*>(partial + ((size_t)s * bps + blockIdx.x) * N_A);
    const float4* ls = reinterpret_cast<const float4*>(lc);
    for (int i = threadIdx.x; i < N_A / 4; i += BLK) po[i] = ls[i];
}

// ---------------- Fallback path (ws too small): global-atomic scatter --------
__global__ __launch_bounds__(256) void coord_scatter(
    const float* __restrict__ vec, const int* __restrict__ atom,
    float* __restrict__ coords)
{
    const int P4 = S_SYS * E_PAIRS / 4;
    int stride = gridDim.x * blockDim.x;
    for (int t = blockIdx.x * blockDim.x + threadIdx.x; t < P4; t += stride) {
        const float4* v4 = reinterpret_cast<const float4*>(vec) + 3ull * (unsigned)t;
        float4 A = v4[0], B = v4[1], C = v4[2];
        int4 id = reinterpret_cast<const int4*>(atom)[t];
        int s = (t * 4) / E_PAIRS;
        float* cs = coords + s * N_A;
        float px[4] = {A.x, A.w, B.z, C.y};
        float py[4] = {A.y, B.x, B.w, C.z};
        float pz[4] = {A.z, B.y, C.x, C.w};
        int ids[4]  = {id.x, id.y, id.z, id.w};
        #pragma unroll
        for (int j = 0; j < 4; ++j) {
            float d = sqrtf(px[j]*px[j] + py[j]*py[j] + pz[j]*pz[j]);
            float y = (d - 4.4f) / 1.1f;
            float z;
            if (y <= 0.0f)      z = 1.0f;
            else if (y >= 1.0f) z = 0.0f;
            else { float u = y - 1.0f; z = u * u * (1.0f + 2.0f * y); }
            if (z != 0.0f) unsafeAtomicAdd(&cs[ids[j]], z);
        }
    }
}

// Kernel 2: sum bps partials per atom, then KDE onto 16 bins.
__global__ __launch_bounds__(256) void kde_reduce(
    const float* __restrict__ partial, float* __restrict__ out, int bps)
{
    int s = blockIdx.y;
    int a = blockIdx.x * 256 + threadIdx.x;
    bool valid = (a < N_A);

    float c = 0.0f;
    if (valid) {
        const float* p = partial + (size_t)s * bps * N_A + a;
        for (int b = 0; b < bps; ++b) c += p[(size_t)b * N_A];
    }

    float vals[NBINS];
    #pragma unroll
    for (int k = 0; k < NBINS; ++k) {
        float d = c - (float)k;
        vals[k] = valid ? expf(-2.0f * d * d) : 0.0f;  // 0.5/SIGMA2 == 2
    }

    #pragma unroll
    for (int k = 0; k < NBINS; ++k) {
        #pragma unroll
        for (int off = 32; off > 0; off >>= 1)
            vals[k] += __shfl_down(vals[k], off, 64);
    }

    __shared__ float sbin[4][NBINS];
    int wave = threadIdx.x >> 6;
    int lane = threadIdx.x & 63;
    if (lane == 0) {
        #pragma unroll
        for (int k = 0; k < NBINS; ++k) sbin[wave][k] = vals[k];
    }
    __syncthreads();
    if (threadIdx.x < NBINS) {
        float v = sbin[0][threadIdx.x] + sbin[1][threadIdx.x]
                + sbin[2][threadIdx.x] + sbin[3][threadIdx.x];
        unsafeAtomicAdd(&out[s * NBINS + threadIdx.x], v);
    }
}

extern "C" void kernel_launch(void* const* d_in, const int* in_sizes, int n_in,
                              void* d_out, int out_size, void* d_ws, size_t ws_size,
                              hipStream_t stream) {
    const float* vec  = (const float*)d_in[0];   // [S,E,3] f32
    const int*   atom = (const int*)d_in[1];     // [S,E] i32
    float* out = (float*)d_out;                  // [S,16] f32
    float* ws  = (float*)d_ws;

    hipMemsetAsync(out, 0, (size_t)S_SYS * NBINS * sizeof(float), stream);

    int bps = (int)(ws_size / ((size_t)S_SYS * N_A * sizeof(float)));
    if (bps > BPS_MAX) bps = BPS_MAX;

    dim3 g2((N_A + 255) / 256, S_SYS);

    if (bps >= 4) {
        dim3 g1(bps, S_SYS);
        coord_lds<<<g1, BLK, 0, stream>>>(vec, atom, ws, bps);
        kde_reduce<<<g2, 256, 0, stream>>>(ws, out, bps);
    } else {
        hipMemsetAsync(ws, 0, (size_t)S_SYS * N_A * sizeof(float), stream);
        coord_scatter<<<2048, 256, 0, stream>>>(vec, atom, ws);
        kde_reduce<<<g2, 256, 0, stream>>>(ws, out, 1);
    }
}